// Round 4
// baseline (1952.910 us; speedup 1.0000x reference)
//
#include <hip/hip_runtime.h>
#include <cstddef>
#include <cstdint>

#define NB 64
#define ND 1024
#define NO 31
#define NSTEPS 16
#define KS 62            // k-splits (k-chunk = 512 k-units, never crosses an opcode)
#define KT32 992         // total K32 steps = 31*1024/32
#define KC32 16          // K32 steps per block
#define GRID 496         // 8 n-tiles x 62 k-splits; 2 blocks/CU -> co-resident

typedef _Float16 half8 __attribute__((ext_vector_type(8)));
typedef float floatx4 __attribute__((ext_vector_type(4)));

// ---------------- softmax over opcode logits: W[b][t][o] ----------------
__global__ void softmax_k(const float* __restrict__ logits, float* __restrict__ W) {
    int row = blockIdx.x * blockDim.x + threadIdx.x;  // row = b*16 + t
    if (row >= NB * NSTEPS) return;
    const float* x = logits + (size_t)row * NO;
    float m = -1e30f;
    for (int o = 0; o < NO; ++o) m = fmaxf(m, x[o]);
    float e[NO]; float s = 0.f;
    for (int o = 0; o < NO; ++o) { e[o] = expf(x[o] - m); s += e[o]; }
    float inv = 1.0f / s;
    float* wo = W + (size_t)row * NO;
    for (int o = 0; o < NO; ++o) wo[o] = e[o] * inv;
}

// ---- kconv: Ktf fragment-ordered fp16 B ----
// half8 unit index: (ns*KT32 + kt)*64 + l ; element j of that half8 =
//   B[k][n] with k = kt*32 + (l>>4)*8 + j, n = ns*16 + (l&15),
//   B[k][n] = K[o = k>>10][d = k&1023][n]
__global__ void kconv_k(const float* __restrict__ K, _Float16* __restrict__ Ktf) {
    int gid = blockIdx.x * 256 + threadIdx.x;   // total = 64*992*64 = 4,063,232
    int l  = gid & 63;
    int kt = (gid >> 6) % KT32;
    int ns = gid / (64 * KT32);
    int kbase = kt * 32 + (l >> 4) * 8;         // o constant across the 8 j's
    int n  = ns * 16 + (l & 15);
    int o  = kbase >> 10;
    int d0 = kbase & 1023;
    const float* src = K + ((size_t)o << 20) + (size_t)d0 * ND + n;
    half8 v;
    #pragma unroll
    for (int j = 0; j < 8; ++j) v[j] = (_Float16)src[(size_t)j * ND];
    *(half8*)(Ktf + (size_t)gid * 8) = v;
}

// ---- grid barrier: spread arrivals over 64 cells, block 0 collects, flag release ----
__device__ __forceinline__ void gridbar(unsigned* cells, unsigned* flag,
                                        int blk, unsigned barid) {
    __syncthreads();   // drains each wave's outstanding stores (vmcnt 0 before s_barrier)
    if (threadIdx.x == 0) {
        __threadfence();   // release: write back to coherence point (cross-XCD)
        __hip_atomic_fetch_add(cells + (blk & 63), 1u,
                               __ATOMIC_RELEASE, __HIP_MEMORY_SCOPE_AGENT);
        if (blk == 0) {
            const unsigned want = (unsigned)GRID * barid;
            for (;;) {
                unsigned s = 0;
                #pragma unroll 8
                for (int i = 0; i < 64; ++i)
                    s += __hip_atomic_load(cells + i, __ATOMIC_RELAXED,
                                           __HIP_MEMORY_SCOPE_AGENT);
                if (s >= want) break;
                __builtin_amdgcn_s_sleep(4);
            }
            __hip_atomic_store(flag, barid, __ATOMIC_RELEASE, __HIP_MEMORY_SCOPE_AGENT);
        } else {
            while (__hip_atomic_load(flag, __ATOMIC_RELAXED,
                                     __HIP_MEMORY_SCOPE_AGENT) < barid)
                __builtin_amdgcn_s_sleep(4);
        }
        __threadfence();   // acquire: invalidate stale L1/L2 before cross-block reads
    }
    __syncthreads();
}

// ---- persistent kernel: all 16 steps. B cached in 128 VGPRs for the whole run ----
__global__ __launch_bounds__(256, 2) void persist_k(
    const float* __restrict__ signal, const _Float16* __restrict__ Ktf,
    const float* __restrict__ W, const float* __restrict__ operands,
    float* __restrict__ P, float* __restrict__ h0buf, float* __restrict__ h1buf,
    float* __restrict__ out, unsigned* __restrict__ cells)
{
    __shared__ _Float16 lds_a[64 * 512];   // half8-index: p*64 + b (p = s*4+q), 64 KB
    const int blk = blockIdx.x;
    const int nb = blk & 7, ks = blk >> 3;
    const int tid = threadIdx.x;
    const int l = tid & 63, w = tid >> 6;
    const int o = ks >> 1, d_base = (ks & 1) * 512;
    const int ml = l & 15, q = l >> 4;
    const int ns0 = nb * 8 + w * 2;
    unsigned* flag = cells + 64;

    // ---- load this block's entire B slice ONCE (constant across steps) ----
    const half8* Bp0 = (const half8*)Ktf + ((size_t)ns0 * KT32 + (size_t)ks * KC32) * 64 + l;
    const half8* Bp1 = (const half8*)Ktf + ((size_t)(ns0 + 1) * KT32 + (size_t)ks * KC32) * 64 + l;
    half8 br0[KC32], br1[KC32];
    #pragma unroll
    for (int s = 0; s < KC32; ++s) br0[s] = Bp0[(size_t)s * 64];
    #pragma unroll
    for (int s = 0; s < KC32; ++s) br1[s] = Bp1[(size_t)s * 64];

    float* Pks = P + (size_t)ks * (NB * ND);
    const int ab = tid >> 2, au = tid & 3;   // A-staging roles
    const half8* Ap = (const half8*)lds_a;

    for (int t = 0; t < NSTEPS; ++t) {
        const float* hsrc = (t == 0) ? signal : ((t & 1) ? h0buf : h1buf);

        // ---- stage A: fp32 h * w -> fp16, frag-ordered ----
        {
            float wv = W[((size_t)ab * NSTEPS + t) * NO + o];
            const float* hb = hsrc + (size_t)ab * ND + d_base;
            #pragma unroll 4
            for (int li = 0; li < 16; ++li) {
                int p = li * 4 + au;
                float4 x0 = *(const float4*)(hb + p * 8);
                float4 x1 = *(const float4*)(hb + p * 8 + 4);
                half8 v;
                v[0] = (_Float16)(x0.x * wv); v[1] = (_Float16)(x0.y * wv);
                v[2] = (_Float16)(x0.z * wv); v[3] = (_Float16)(x0.w * wv);
                v[4] = (_Float16)(x1.x * wv); v[5] = (_Float16)(x1.y * wv);
                v[6] = (_Float16)(x1.z * wv); v[7] = (_Float16)(x1.w * wv);
                *(half8*)&lds_a[(size_t)(p * 64 + ab) * 8] = v;
            }
        }
        __syncthreads();

        floatx4 acc[2][4] = {};
        #pragma unroll
        for (int s = 0; s < KC32; ++s) {
            int abase = (s * 4 + q) * 64 + ml;
            half8 a0 = Ap[abase];
            half8 a1 = Ap[abase + 16];
            half8 a2 = Ap[abase + 32];
            half8 a3 = Ap[abase + 48];
            acc[0][0] = __builtin_amdgcn_mfma_f32_16x16x32_f16(a0, br0[s], acc[0][0], 0, 0, 0);
            acc[0][1] = __builtin_amdgcn_mfma_f32_16x16x32_f16(a1, br0[s], acc[0][1], 0, 0, 0);
            acc[0][2] = __builtin_amdgcn_mfma_f32_16x16x32_f16(a2, br0[s], acc[0][2], 0, 0, 0);
            acc[0][3] = __builtin_amdgcn_mfma_f32_16x16x32_f16(a3, br0[s], acc[0][3], 0, 0, 0);
            acc[1][0] = __builtin_amdgcn_mfma_f32_16x16x32_f16(a0, br1[s], acc[1][0], 0, 0, 0);
            acc[1][1] = __builtin_amdgcn_mfma_f32_16x16x32_f16(a1, br1[s], acc[1][1], 0, 0, 0);
            acc[1][2] = __builtin_amdgcn_mfma_f32_16x16x32_f16(a2, br1[s], acc[1][2], 0, 0, 0);
            acc[1][3] = __builtin_amdgcn_mfma_f32_16x16x32_f16(a3, br1[s], acc[1][3], 0, 0, 0);
        }

        // ---- write partial (C/D layout: col = l&15, row = (l>>4)*4 + r) ----
        #pragma unroll
        for (int nsub = 0; nsub < 2; ++nsub) {
            int n = (ns0 + nsub) * 16 + ml;
            #pragma unroll
            for (int mt = 0; mt < 4; ++mt) {
                #pragma unroll
                for (int r = 0; r < 4; ++r) {
                    int b = mt * 16 + q * 4 + r;
                    Pks[(size_t)b * ND + n] = acc[nsub][mt][r];
                }
            }
        }

        gridbar(cells, flag, blk, (unsigned)(2 * t + 1));

        // ---- update phase: blocks 0..63, block b handles batch row b ----
        if (blk < NB) {
            const int b = blk;
            float gl = operands[((size_t)b * NSTEPS + t) * 4 + 3];
            float g  = 1.0f / (1.0f + expf(-gl));
            const float* prow = P + (size_t)b * ND + tid * 4;
            float sx = 0.f, sy = 0.f, sz = 0.f, sw = 0.f;
            #pragma unroll 8
            for (int k2 = 0; k2 < KS; ++k2) {
                float4 v = *(const float4*)(prow + (size_t)k2 * (NB * ND));
                sx += v.x; sy += v.y; sz += v.z; sw += v.w;
            }
            float4 hv = *(const float4*)(hsrc + (size_t)b * ND + tid * 4);
            float* hdst = (t == NSTEPS - 1) ? out : ((t & 1) ? h1buf : h0buf);
            float4 ov;
            ov.x = g * sx + (1.f - g) * hv.x;
            ov.y = g * sy + (1.f - g) * hv.y;
            ov.z = g * sz + (1.f - g) * hv.z;
            ov.w = g * sw + (1.f - g) * hv.w;
            *(float4*)(hdst + (size_t)b * ND + tid * 4) = ov;
        }

        if (t < NSTEPS - 1)
            gridbar(cells, flag, blk, (unsigned)(2 * t + 2));
    }
}

extern "C" void kernel_launch(void* const* d_in, const int* in_sizes, int n_in,
                              void* d_out, int out_size, void* d_ws, size_t ws_size,
                              hipStream_t stream)
{
    const float* logits   = (const float*)d_in[0];  // (64,16,31)
    const float* operands = (const float*)d_in[1];  // (64,16,4)
    const float* signal   = (const float*)d_in[2];  // (64,1024)
    const float* opk      = (const float*)d_in[3];  // (31,1024,1024)
    float* out = (float*)d_out;
    char* ws = (char*)d_ws;

    size_t offCNT = 0;                                 // 512 B barrier state
    size_t offW   = 512;                               // 127 KB weights
    size_t offP   = 512 + 130560;                      // = 131072; P: 15.5 MB
    size_t offH   = offP + (size_t)KS * NB * ND * 4;
    size_t offK   = offH + 2ull * NB * ND * 4;         // Ktf: 62 MB fp16

    unsigned* cells = (unsigned*)(ws + offCNT);
    float*    W  = (float*)(ws + offW);
    float*    P  = (float*)(ws + offP);
    float*    h0 = (float*)(ws + offH);
    float*    h1 = h0 + NB * ND;
    _Float16* Ktf = (_Float16*)(ws + offK);

    hipMemsetAsync(ws, 0, 512, stream);   // zero barrier cells + flag
    softmax_k<<<dim3(4), 256, 0, stream>>>(logits, W);
    kconv_k<<<dim3(15872), 256, 0, stream>>>(opk, Ktf);
    persist_k<<<dim3(GRID), 256, 0, stream>>>(signal, Ktf, W, operands,
                                              P, h0, h1, out, cells);
}

// Round 5
// 639.482 us; speedup vs baseline: 3.0539x; 3.0539x over previous
//
#include <hip/hip_runtime.h>
#include <cstddef>
#include <cstdint>

#define NB 64
#define ND 1024
#define NO 31
#define NSTEPS 16
#define KS 62            // k-splits (k-chunk = 512 k-units, never crosses an opcode)
#define KT32 992         // total K32 steps = 31*1024/32
#define KC32 16          // K32 steps per block

typedef _Float16 half8 __attribute__((ext_vector_type(8)));
typedef float floatx4 __attribute__((ext_vector_type(4)));

// rolling waits: vmcnt(N) with lgkm/exp don't-care (gfx9 encoding)
__device__ __forceinline__ void wait_vm2() {
    __builtin_amdgcn_s_waitcnt(0x0f72);   // vmcnt(2)
    __builtin_amdgcn_sched_barrier(0);    // keep ds_reads below the wait
}
__device__ __forceinline__ void wait_vm0() {
    __builtin_amdgcn_s_waitcnt(0x0f70);   // vmcnt(0)
    __builtin_amdgcn_sched_barrier(0);
}
// async global->LDS DMA, 16 B/lane; lds base wave-uniform, lane i lands at base+16*i
__device__ __forceinline__ void gld_lds16(const _Float16* g, _Float16* l) {
    __builtin_amdgcn_global_load_lds(
        (__attribute__((address_space(1))) void*)g,
        (__attribute__((address_space(3))) void*)l, 16, 0, 0);
}

// ---------------- softmax over opcode logits: W[b][t][o] ----------------
__global__ void softmax_k(const float* __restrict__ logits, float* __restrict__ W) {
    int row = blockIdx.x * blockDim.x + threadIdx.x;  // row = b*16 + t
    if (row >= NB * NSTEPS) return;
    const float* x = logits + (size_t)row * NO;
    float m = -1e30f;
    for (int o = 0; o < NO; ++o) m = fmaxf(m, x[o]);
    float e[NO]; float s = 0.f;
    for (int o = 0; o < NO; ++o) { e[o] = expf(x[o] - m); s += e[o]; }
    float inv = 1.0f / s;
    float* wo = W + (size_t)row * NO;
    for (int o = 0; o < NO; ++o) wo[o] = e[o] * inv;
}

// ---- kconv: Ktf fragment-ordered fp16 B ----
// half8 unit index: (ns*KT32 + kt)*64 + l ; element j of that half8 =
//   B[k][n] with k = kt*32 + (l>>4)*8 + j, n = ns*16 + (l&15),
//   B[k][n] = K[o = k>>10][d = k&1023][n]
__global__ void kconv_k(const float* __restrict__ K, _Float16* __restrict__ Ktf) {
    int gid = blockIdx.x * 256 + threadIdx.x;   // total = 64*992*64 = 4,063,232
    int l  = gid & 63;
    int kt = (gid >> 6) % KT32;
    int ns = gid / (64 * KT32);
    int kbase = kt * 32 + (l >> 4) * 8;         // o constant across the 8 j's
    int n  = ns * 16 + (l & 15);
    int o  = kbase >> 10;
    int d0 = kbase & 1023;
    const float* src = K + ((size_t)o << 20) + (size_t)d0 * ND + n;
    half8 v;
    #pragma unroll
    for (int j = 0; j < 8; ++j) v[j] = (_Float16)src[(size_t)j * ND];
    *(half8*)(Ktf + (size_t)gid * 8) = v;
}

// ---- GEMM: P[ks][b][n] = sum over block's k-chunk of (w*h) @ B ----
// grid (8 n-tiles of 128, 62 k-splits), 256 thr. Wave = M64 x N32.
// B double-buffered via global_load_lds DMA; each wave stages exactly the two
// 1 KB units it consumes -> no barrier in the K-loop, rolling vmcnt(2).
__global__ __launch_bounds__(256) void gemm_k(
    const float* __restrict__ h, const _Float16* __restrict__ Ktf,
    const float* __restrict__ W, float* __restrict__ P, int step)
{
    __shared__ _Float16 lds_a[64 * 512];        // 64 KB, frag-ordered A
    __shared__ _Float16 lds_b[2][8][512];       // 2 bufs x 8 units x 1 KB = 16 KB
    const int nb = blockIdx.x;                  // 0..7
    const int ks = blockIdx.y;                  // 0..61
    const int tid = threadIdx.x;
    const int l = tid & 63, w = tid >> 6;
    const int o = ks >> 1, d_base = (ks & 1) * 512;
    const int ml = l & 15, q = l >> 4;
    const int ns0 = nb * 8 + w * 2;             // this wave's two n-subtiles
    const size_t kt0 = (size_t)ks * KC32;

    // per-lane global addresses of this wave's two B units at chunk 0
    const _Float16* gB0 = Ktf + (((size_t)ns0 * KT32 + kt0) << 9) + (l << 3);
    const _Float16* gB1 = Ktf + ((((size_t)ns0 + 1) * KT32 + kt0) << 9) + (l << 3);

    // prefetch chunks 0 and 1 (DMA; drained by the A-stage __syncthreads)
    gld_lds16(gB0,       &lds_b[0][2 * w][0]);
    gld_lds16(gB1,       &lds_b[0][2 * w + 1][0]);
    gld_lds16(gB0 + 512, &lds_b[1][2 * w][0]);
    gld_lds16(gB1 + 512, &lds_b[1][2 * w + 1][0]);

    // ---- stage A: fp32 h * w -> fp16, frag-ordered ----
    {
        int ab = tid >> 2, au = tid & 3;
        float wv = W[((size_t)ab * NSTEPS + step) * NO + o];
        const float* hb = h + (size_t)ab * ND + d_base;
        #pragma unroll 4
        for (int li = 0; li < 16; ++li) {
            int p = li * 4 + au;
            float4 x0 = *(const float4*)(hb + p * 8);
            float4 x1 = *(const float4*)(hb + p * 8 + 4);
            half8 v;
            v[0] = (_Float16)(x0.x * wv); v[1] = (_Float16)(x0.y * wv);
            v[2] = (_Float16)(x0.z * wv); v[3] = (_Float16)(x0.w * wv);
            v[4] = (_Float16)(x1.x * wv); v[5] = (_Float16)(x1.y * wv);
            v[6] = (_Float16)(x1.z * wv); v[7] = (_Float16)(x1.w * wv);
            *(half8*)&lds_a[(size_t)(p * 64 + ab) * 8] = v;
        }
    }
    __syncthreads();

    const half8* Ap = (const half8*)lds_a;
    floatx4 acc[2][4] = {};

    #pragma unroll
    for (int s = 0; s < 15; ++s) {
        wait_vm2();                              // chunk s resident (s+1 may fly)
        int buf = s & 1;
        half8 b0 = *(const half8*)&lds_b[buf][2 * w][l * 8];
        half8 b1 = *(const half8*)&lds_b[buf][2 * w + 1][l * 8];
        int abase = (s * 4 + q) * 64 + ml;
        half8 a0 = Ap[abase];
        half8 a1 = Ap[abase + 16];
        half8 a2 = Ap[abase + 32];
        half8 a3 = Ap[abase + 48];
        acc[0][0] = __builtin_amdgcn_mfma_f32_16x16x32_f16(a0, b0, acc[0][0], 0, 0, 0);
        acc[0][1] = __builtin_amdgcn_mfma_f32_16x16x32_f16(a1, b0, acc[0][1], 0, 0, 0);
        acc[0][2] = __builtin_amdgcn_mfma_f32_16x16x32_f16(a2, b0, acc[0][2], 0, 0, 0);
        acc[0][3] = __builtin_amdgcn_mfma_f32_16x16x32_f16(a3, b0, acc[0][3], 0, 0, 0);
        acc[1][0] = __builtin_amdgcn_mfma_f32_16x16x32_f16(a0, b1, acc[1][0], 0, 0, 0);
        acc[1][1] = __builtin_amdgcn_mfma_f32_16x16x32_f16(a1, b1, acc[1][1], 0, 0, 0);
        acc[1][2] = __builtin_amdgcn_mfma_f32_16x16x32_f16(a2, b1, acc[1][2], 0, 0, 0);
        acc[1][3] = __builtin_amdgcn_mfma_f32_16x16x32_f16(a3, b1, acc[1][3], 0, 0, 0);
        if (s < 14) {                            // stage chunk s+2 into buf s&1
            gld_lds16(gB0 + (size_t)(s + 2) * 512, &lds_b[buf][2 * w][0]);
            gld_lds16(gB1 + (size_t)(s + 2) * 512, &lds_b[buf][2 * w + 1][0]);
        }
    }
    {   // peeled s = 15: only its own 2 loads outstanding -> need vmcnt(0)
        wait_vm0();
        half8 b0 = *(const half8*)&lds_b[1][2 * w][l * 8];
        half8 b1 = *(const half8*)&lds_b[1][2 * w + 1][l * 8];
        int abase = (15 * 4 + q) * 64 + ml;
        half8 a0 = Ap[abase];
        half8 a1 = Ap[abase + 16];
        half8 a2 = Ap[abase + 32];
        half8 a3 = Ap[abase + 48];
        acc[0][0] = __builtin_amdgcn_mfma_f32_16x16x32_f16(a0, b0, acc[0][0], 0, 0, 0);
        acc[0][1] = __builtin_amdgcn_mfma_f32_16x16x32_f16(a1, b0, acc[0][1], 0, 0, 0);
        acc[0][2] = __builtin_amdgcn_mfma_f32_16x16x32_f16(a2, b0, acc[0][2], 0, 0, 0);
        acc[0][3] = __builtin_amdgcn_mfma_f32_16x16x32_f16(a3, b0, acc[0][3], 0, 0, 0);
        acc[1][0] = __builtin_amdgcn_mfma_f32_16x16x32_f16(a0, b1, acc[1][0], 0, 0, 0);
        acc[1][1] = __builtin_amdgcn_mfma_f32_16x16x32_f16(a1, b1, acc[1][1], 0, 0, 0);
        acc[1][2] = __builtin_amdgcn_mfma_f32_16x16x32_f16(a2, b1, acc[1][2], 0, 0, 0);
        acc[1][3] = __builtin_amdgcn_mfma_f32_16x16x32_f16(a3, b1, acc[1][3], 0, 0, 0);
    }

    // ---- epilogue: C/D col = l&15, row = (l>>4)*4 + r (verified mapping) ----
    float* Pks = P + (size_t)ks * (NB * ND);
    #pragma unroll
    for (int nsub = 0; nsub < 2; ++nsub) {
        int n = (ns0 + nsub) * 16 + ml;
        #pragma unroll
        for (int mt = 0; mt < 4; ++mt) {
            #pragma unroll
            for (int r = 0; r < 4; ++r) {
                int b = mt * 16 + q * 4 + r;
                Pks[(size_t)b * ND + n] = acc[nsub][mt][r];
            }
        }
    }
}

// ---- reduce KS partials + gated update (float4 per thread) ----
__global__ void update_k(const float* __restrict__ hin, const float* __restrict__ P,
                         const float* __restrict__ operands, float* __restrict__ hout,
                         int step)
{
    int idx = blockIdx.x * blockDim.x + threadIdx.x;   // 16384 threads, float4 each
    int b = idx >> 8, n4 = (idx & 255) * 4;
    float gl = operands[((size_t)b * NSTEPS + step) * 4 + 3];
    float g  = 1.0f / (1.0f + expf(-gl));
    const float* p = P + (size_t)b * ND + n4;
    float sx = 0.f, sy = 0.f, sz = 0.f, sw = 0.f;
    #pragma unroll 2
    for (int ks = 0; ks < KS; ++ks) {
        float4 v = *(const float4*)(p + (size_t)ks * (NB * ND));
        sx += v.x; sy += v.y; sz += v.z; sw += v.w;
    }
    const float* hb = hin + (size_t)b * ND + n4;
    float4 hv = *(const float4*)hb;
    float4 outv;
    outv.x = g * sx + (1.f - g) * hv.x;
    outv.y = g * sy + (1.f - g) * hv.y;
    outv.z = g * sz + (1.f - g) * hv.z;
    outv.w = g * sw + (1.f - g) * hv.w;
    *(float4*)(hout + (size_t)b * ND + n4) = outv;
}

extern "C" void kernel_launch(void* const* d_in, const int* in_sizes, int n_in,
                              void* d_out, int out_size, void* d_ws, size_t ws_size,
                              hipStream_t stream)
{
    const float* logits   = (const float*)d_in[0];  // (64,16,31)
    const float* operands = (const float*)d_in[1];  // (64,16,4)
    const float* signal   = (const float*)d_in[2];  // (64,1024)
    const float* opk      = (const float*)d_in[3];  // (31,1024,1024)
    float* out = (float*)d_out;
    char* ws = (char*)d_ws;

    size_t offW = 0;                                   // 128 KB
    size_t offP = 131072;                              // KS*64*1024*4 = 15.5 MB
    size_t offH = offP + (size_t)KS * NB * ND * 4;
    size_t offK = offH + 2ull * NB * ND * 4;           // Ktf: 62 MB fp16

    float*    W  = (float*)(ws + offW);
    float*    P  = (float*)(ws + offP);
    float*    h0 = (float*)(ws + offH);
    float*    h1 = h0 + NB * ND;
    _Float16* Ktf = (_Float16*)(ws + offK);

    softmax_k<<<dim3(4), 256, 0, stream>>>(logits, W);
    kconv_k<<<dim3(15872), 256, 0, stream>>>(opk, Ktf);

    const float* hc = signal;
    float* hn = h0;
    for (int t = 0; t < NSTEPS; ++t) {
        gemm_k<<<dim3(8, KS), 256, 0, stream>>>(hc, Ktf, W, P, t);
        float* dst = (t == NSTEPS - 1) ? out : hn;
        update_k<<<dim3(128), 128, 0, stream>>>(hc, P, operands, dst, t);
        hc = dst;
        hn = (hn == h0) ? h1 : h0;
    }
}